// Round 6
// baseline (2673.134 us; speedup 1.0000x reference)
//
#include <hip/hip_runtime.h>
#include <stdint.h>

typedef __attribute__((ext_vector_type(8))) short short8;
typedef __attribute__((ext_vector_type(4))) float f32x4;
typedef unsigned long long u64;

constexpr int cB = 32, cT = 512, cD = 512, cH = 512;
constexpr int cKI = 6 * cH;   // 3072
constexpr int NWG = 32;       // persistent lstm WGs (blockIdx 0..31)
constexpr int THR = 320;
constexpr int HP  = 520;      // h_lds row pitch (shorts)
constexpr int RNG = 3;        // pi prefetch ring depth
constexpr int PIP = 40;       // piL / gemm LDS row pitch (shorts)
constexpr int GK = 24, GN = 128;   // gemm tile grid

// flags int layout (memset 0 each launch):
//   [512..639] per-n-block gemm tile counters (GN), [640] total tiles done
constexpr int OFF_PIL  = 32 * HP * 2;                      // 33280
constexpr int OFF_PS   = OFF_PIL + RNG * 6 * 16 * PIP * 2; // 56320
constexpr int OFF_C    = OFF_PS + 5 * 16 * 36 * 4;         // 67840
constexpr int OFF_BS   = OFF_C + 512 * 4;                  // 69888
constexpr int OFF_LEN  = OFF_BS + 80 * 4;                  // 70208
constexpr int SMEM_SZ  = OFF_LEN + 32 * 4 + 16;            // 70352

__device__ __forceinline__ float bf2f(unsigned short u) {
  union { unsigned int i; float f; } x; x.i = ((unsigned int)u) << 16; return x.f;
}
__device__ __forceinline__ unsigned short f2bf(float f) {
  union { float f; unsigned int i; } x; x.f = f;
  return (unsigned short)((x.i + 0x7fffu + ((x.i >> 16) & 1u)) >> 16);
}
__device__ __forceinline__ float sigm(float v) { return 1.0f / (1.0f + __expf(-v)); }
__device__ __forceinline__ float tanh_f(float v) { return 2.0f / (1.0f + __expf(-2.0f * v)) - 1.0f; }

__global__ __launch_bounds__(THR, 1) void fused_lstm(
    const float* __restrict__ x,    // [B][T][D]
    const float* __restrict__ Wi,   // [6H][D]
    const float* __restrict__ bi,   // [6H]
    const float* __restrict__ Ws,   // [5H][H]
    const float* __restrict__ bs,   // [5H]
    const int* __restrict__ lengths,
    unsigned short* __restrict__ pi,   // [T][6H][B] bf16 (ws)
    u64* __restrict__ hbuf,            // [2][8192] tagged-u64 (ws, 128KB)
    int* __restrict__ flags,
    float* __restrict__ out)           // ys[B][T][H], hT[B][H], cT[B][H]
{
  __shared__ __align__(16) unsigned char smem[SMEM_SZ];
  const int tid = threadIdx.x;
  const int lane = tid & 63;
  const int w = tid >> 6;

  if (blockIdx.x >= NWG) {
    // ================= GEMM tile branch: pi[t][k][b] = x . Wi + bi =================
    const int gb = (int)blockIdx.x - NWG;
    const int kb = gb % GK, nbk = gb / GK;
    const int k0 = kb * 128, n0 = nbk * 128;     // n = t*32 + b
    unsigned short* Ai = (unsigned short*)smem;            // 128 x PIP shorts
    unsigned short* Bi = (unsigned short*)(smem + 10240);  // 128 x PIP shorts
    const int wm = w & 1, wn = w >> 1;

    f32x4 acc[4][4];
    #pragma unroll
    for (int i = 0; i < 4; i++)
      #pragma unroll
      for (int j = 0; j < 4; j++) acc[i][j] = (f32x4){0.f, 0.f, 0.f, 0.f};

    for (int kk = 0; kk < cD; kk += 32) {
      __syncthreads();
      for (int idx = tid; idx < 1024; idx += THR) {
        int r = idx >> 3, ch = idx & 7;
        int na = n0 + r, bb = na & 31, tt = na >> 5;
        float4 va = *(const float4*)(x + ((size_t)bb * cT + tt) * cD + kk + ch * 4);
        ushort4 pa; pa.x = f2bf(va.x); pa.y = f2bf(va.y); pa.z = f2bf(va.z); pa.w = f2bf(va.w);
        *(ushort4*)(Ai + r * PIP + ch * 4) = pa;
        float4 vb = *(const float4*)(Wi + (size_t)(k0 + r) * cD + kk + ch * 4);
        ushort4 pb; pb.x = f2bf(vb.x); pb.y = f2bf(vb.y); pb.z = f2bf(vb.z); pb.w = f2bf(vb.w);
        *(ushort4*)(Bi + r * PIP + ch * 4) = pb;
      }
      __syncthreads();
      if (w < 4) {
        short8 af[4], bfr[4];
        const int q = lane >> 4;
        #pragma unroll
        for (int mi = 0; mi < 4; mi++)
          af[mi] = *(const short8*)(Ai + (wm * 64 + mi * 16 + (lane & 15)) * PIP + q * 8);
        #pragma unroll
        for (int ni = 0; ni < 4; ni++)
          bfr[ni] = *(const short8*)(Bi + (wn * 64 + ni * 16 + (lane & 15)) * PIP + q * 8);
        #pragma unroll
        for (int mi = 0; mi < 4; mi++)
          #pragma unroll
          for (int ni = 0; ni < 4; ni++)
            acc[mi][ni] = __builtin_amdgcn_mfma_f32_16x16x32_bf16(af[mi], bfr[ni], acc[mi][ni], 0, 0, 0);
      }
    }
    if (w < 4) {
      #pragma unroll
      for (int ni = 0; ni < 4; ni++) {
        int kl = wn * 64 + ni * 16 + (lane & 15);
        float bv = bi[k0 + kl];
        #pragma unroll
        for (int mi = 0; mi < 4; mi++) {
          int nl = wm * 64 + mi * 16 + (lane >> 4) * 4;
          int nb = n0 + nl;
          int b0 = nb & 31, tt = nb >> 5;
          f32x4 a = acc[mi][ni];
          unsigned short v0 = f2bf(a.x + bv), v1 = f2bf(a.y + bv);
          unsigned short v2 = f2bf(a.z + bv), v3 = f2bf(a.w + bv);
          u64 pk = (u64)v0 | ((u64)v1 << 16) | ((u64)v2 << 32) | ((u64)v3 << 48);
          __hip_atomic_store((u64*)(pi + ((size_t)tt * cKI + k0 + kl) * cB + b0), pk,
                             __ATOMIC_RELAXED, __HIP_MEMORY_SCOPE_AGENT);
        }
      }
    }
    __syncthreads();   // drains vmcnt: all pi stores acked before counter inc
    if (tid == 0) {
      __hip_atomic_fetch_add(flags + 512 + nbk, 1, __ATOMIC_RELAXED, __HIP_MEMORY_SCOPE_AGENT);
      __hip_atomic_fetch_add(flags + 640, 1, __ATOMIC_RELAXED, __HIP_MEMORY_SCOPE_AGENT);
    }
    return;
  }

  // ================= LSTM persistent branch: tagged-h exchange, 2 barriers/step =================
  unsigned short* h_lds  = (unsigned short*)smem;                // [32][HP]
  unsigned short* piL    = (unsigned short*)(smem + OFF_PIL);    // [RNG][6*16][PIP]
  float* ps_lds          = (float*)(smem + OFF_PS);              // [5*16][36]
  float* c_lds           = (float*)(smem + OFF_C);               // [b*16+c]
  float* bs_lds          = (float*)(smem + OFF_BS);              // [80]
  int*   len_lds         = (int*)(smem + OFF_LEN);               // [32]

  const int wg = blockIdx.x;
  const int ci0 = wg * 16;
  const int mc = lane & 15;
  const int kq = lane >> 4;

  // Ws B-fragments in registers (verified layout)
  short8 bfrag[16];
  {
    const float* wsrow = Ws + (size_t)(w * cH + ci0 + mc) * cH;
    #pragma unroll
    for (int kt = 0; kt < 16; kt++) {
      float4 f0 = *(const float4*)(wsrow + kt * 32 + kq * 8);
      float4 f1 = *(const float4*)(wsrow + kt * 32 + kq * 8 + 4);
      short8 pk;
      pk[0] = (short)f2bf(f0.x); pk[1] = (short)f2bf(f0.y);
      pk[2] = (short)f2bf(f0.z); pk[3] = (short)f2bf(f0.w);
      pk[4] = (short)f2bf(f1.x); pk[5] = (short)f2bf(f1.y);
      pk[6] = (short)f2bf(f1.z); pk[7] = (short)f2bf(f1.w);
      bfrag[kt] = pk;
    }
  }
  if (tid < 80) bs_lds[tid] = bs[(tid >> 4) * cH + ci0 + (tid & 15)];
  if (tid < cB) len_lds[tid] = lengths[tid];
  for (int q = tid; q < 512; q += THR) c_lds[q] = 0.0f;
  for (int q = tid; q < 32 * HP / 4; q += THR) ((u64*)h_lds)[q] = 0ull;   // h0 = 0

  // initial pi readiness: n-block 0 covers t=0..3. All threads self-gate; bounded.
  {
    int guard = 0;
    while (__hip_atomic_load(flags + 512, __ATOMIC_RELAXED, __HIP_MEMORY_SCOPE_AGENT) < GK) {
      __builtin_amdgcn_s_sleep(8);
      if (++guard > 1000000) break;   // loud-fail, never wedge
    }
    asm volatile("" ::: "memory");    // fence: no pi-load hoisting above the gate
  }
  // pi ring prologue: t=0 -> slot0, t=1 -> slot1
  for (int s = 0; s < 2; s++) {
    const unsigned short* pit = pi + (size_t)s * cKI * cB;
    for (int j = tid; j < 384; j += THR) {
      int g = j >> 6, rem = j & 63, c = rem >> 2, q = rem & 3;
      uint4 v = *(const uint4*)(pit + ((size_t)g * cH + ci0 + c) * cB + q * 8);
      *(uint4*)(piL + s * (6 * 16 * PIP) + (g * 16 + c) * PIP + q * 8) = v;
    }
  }
  __syncthreads();

  bool all_ready = false;   // gemm fully done (per-thread)
  bool dead = false;        // poll kill switch (per-thread, wave-uniform)
  float hprev0 = 0.0f, hprev1 = 0.0f;   // register-carried h for this thread's (b,c)

  for (int t = 0; t < cT; t++) {
    const bool last = (t == cT - 1);
    const bool pf = (t + 2) < cT;
    // [R] pi readiness for step t+2 (self-gating, no barrier; short-circuits when gemm done)
    if (pf && !all_ready) {
      int guard = 0;
      while (true) {
        int tot = __hip_atomic_load(flags + 640, __ATOMIC_RELAXED, __HIP_MEMORY_SCOPE_AGENT);
        if (tot >= GK * GN) { all_ready = true; break; }
        int v = __hip_atomic_load(flags + 512 + ((t + 2) >> 2), __ATOMIC_RELAXED, __HIP_MEMORY_SCOPE_AGENT);
        if (v >= GK) break;
        __builtin_amdgcn_s_sleep(4);
        if (++guard > 200000) { all_ready = true; break; }   // loud-fail
      }
      asm volatile("" ::: "memory");
    }
    // [P] pi loads for step t+2 (fire-and-forget, in flight across the poll)
    uint4 pv0, pv1;
    const int slot_w = (t + 2) % RNG;
    if (pf) {
      const unsigned short* pit = pi + (size_t)(t + 2) * cKI * cB;
      { int g = tid >> 6, rem = tid & 63, c = rem >> 2, q = rem & 3;
        pv0 = *(const uint4*)(pit + ((size_t)g * cH + ci0 + c) * cB + q * 8); }
      int j1 = tid + THR;
      if (j1 < 384) { int g = j1 >> 6, rem = j1 & 63, c = rem >> 2, q = rem & 3;
        pv1 = *(const uint4*)(pit + ((size_t)g * cH + ci0 + c) * cB + q * 8); }
    }
    // [A'] tagged-h poll: accept when every word carries tag t. Self-validating:
    // no producer drain, no flag, no separate data load.
    u64 ha[26];
    if (t > 0 && !dead) {
      const u64* hs = hbuf + (size_t)(t & 1) * 8192;
      const unsigned tg = (unsigned)t;
      int itc = 0;
      while (true) {
        bool ok = true;
        #pragma unroll
        for (int k = 0; k < 26; k++) {
          int idx = tid + k * THR;
          if (idx < 8192) {
            ha[k] = __hip_atomic_load(hs + idx, __ATOMIC_RELAXED, __HIP_MEMORY_SCOPE_AGENT);
            ok = ok && (((unsigned)ha[k] & 0xFFFFu) == tg)
                    && (((unsigned)(ha[k] >> 32) & 0xFFFFu) == tg);
          }
        }
        if (__all(ok)) break;
        if (++itc > 100000) { dead = true; break; }   // kill switch: loud-fail
      }
      // [C] unpack to h_lds (bf16 pairs from tagged words)
      #pragma unroll
      for (int k = 0; k < 26; k++) {
        int idx = tid + k * THR;
        if (idx < 8192) {
          int b = idx >> 8, ch = idx & 255;
          unsigned lo = (unsigned)ha[k], hi = (unsigned)(ha[k] >> 32);
          *(unsigned*)(h_lds + b * HP + ch * 2) = (lo >> 16) | (hi & 0xFFFF0000u);
        }
      }
    }
    __syncthreads();   // B1: h_lds visible (late drain: prior stores long retired)

    // [D] MFMA: wave w computes ps[:, gate w] : 32x16, K=512 (Ws in registers)
    f32x4 acc0 = (f32x4){0.f,0.f,0.f,0.f}, acc1 = (f32x4){0.f,0.f,0.f,0.f};
    #pragma unroll
    for (int kt = 0; kt < 16; kt++) {
      int kc = kt * 4 + kq;
      short8 a0 = *(const short8*)(h_lds + mc * HP + kc * 8);
      short8 a1 = *(const short8*)(h_lds + (16 + mc) * HP + kc * 8);
      acc0 = __builtin_amdgcn_mfma_f32_16x16x32_bf16(a0, bfrag[kt], acc0, 0, 0, 0);
      acc1 = __builtin_amdgcn_mfma_f32_16x16x32_bf16(a1, bfrag[kt], acc1, 0, 0, 0);
    }
    {
      int r0 = kq * 4;   // C layout: col=lane&15 (=c), rows=(lane>>4)*4+reg (=b)
      *(f32x4*)(ps_lds + (w * 16 + mc) * 36 + r0) = acc0;
      *(f32x4*)(ps_lds + (w * 16 + mc) * 36 + r0 + 16) = acc1;
    }
    // [E] pi ring write for t+2
    if (pf) {
      { int g = tid >> 6, rem = tid & 63, c = rem >> 2, q = rem & 3;
        *(uint4*)(piL + slot_w * (6 * 16 * PIP) + (g * 16 + c) * PIP + q * 8) = pv0; }
      int j1 = tid + THR;
      if (j1 < 384) { int g = j1 >> 6, rem = j1 & 63, c = rem >> 2, q = rem & 3;
        *(uint4*)(piL + slot_w * (6 * 16 * PIP) + (g * 16 + c) * PIP + q * 8) = pv1; }
    }
    __syncthreads();   // B2: ps + ring visible

    // [F] gates, c-fast mapping: b=idx>>4, c=idx&15. hold carried in registers.
    const unsigned short* pl = piL + (t % RNG) * (6 * 16 * PIP);
    u64* hb64 = hbuf + (size_t)((t + 1) & 1) * 8192;
    const unsigned tg1 = (unsigned)(t + 1);
    #pragma unroll
    for (int u = 0; u < 2; u++) {
      int idx = tid + u * THR;
      if (idx < 512) {
        int b = idx >> 4, c = idx & 15;
        int col = ci0 + c;
        float a_i = bf2f(pl[(0*16 + c)*PIP + b]) + ps_lds[(0*16 + c)*36 + b] + bs_lds[0*16 + c];
        float a_f = bf2f(pl[(1*16 + c)*PIP + b]) + ps_lds[(1*16 + c)*36 + b] + bs_lds[1*16 + c];
        float a_g = bf2f(pl[(2*16 + c)*PIP + b]) + ps_lds[(2*16 + c)*36 + b] + bs_lds[2*16 + c];
        float a_o = bf2f(pl[(3*16 + c)*PIP + b]) + ps_lds[(3*16 + c)*36 + b] + bs_lds[3*16 + c];
        float a_r = bf2f(pl[(4*16 + c)*PIP + b]) + ps_lds[(4*16 + c)*36 + b] + bs_lds[4*16 + c];
        float p5  = bf2f(pl[(5*16 + c)*PIP + b]);
        float gi = sigm(a_i), gf = sigm(a_f), gg = tanh_f(a_g), go = sigm(a_o), gr = sigm(a_r);
        float cold = c_lds[b * 16 + c];
        float cn = gi * gg + gf * cold;
        float ov = go * tanh_f(cn);
        ov = gr * ov + (1.0f - gr) * p5;
        bool m = (t < len_lds[b]);
        float hold = (u == 0) ? hprev0 : hprev1;
        float hn = m ? ov : hold;
        if (u == 0) hprev0 = hn; else hprev1 = hn;
        c_lds[b * 16 + c] = m ? cn : cold;
        float ovm = m ? ov : 0.0f;
        // publish tagged h first (consumers wait on it), pair-packed u64
        unsigned tw = ((unsigned)f2bf(hn) << 16) | tg1;
        unsigned pr = (unsigned)__shfl_down((int)tw, 1);
        if (!last && (c & 1) == 0) {
          u64 up = (u64)tw | ((u64)pr << 32);
          __hip_atomic_store(hb64 + ((b * cH + col) >> 1), up,
                             __ATOMIC_RELAXED, __HIP_MEMORY_SCOPE_AGENT);
        }
        out[((size_t)b * cT + t) * cH + col] = ovm;
        if (last)
          out[(size_t)cB * cT * cH + (size_t)b * cH + col] = hn;   // hT
      }
    }
    // no end-of-loop barrier: h_lds hazard gone (hold in regs); piL slot reuse
    // and ps_lds are covered by next iteration's B1/B2.
  }

  // cT from local c state (same thread mapping as gates -> no sync needed)
  #pragma unroll
  for (int u = 0; u < 2; u++) {
    int idx = tid + u * THR;
    if (idx < 512) {
      int b = idx >> 4, c = idx & 15;
      out[(size_t)cB * cT * cH + (size_t)cB * cH + (size_t)b * cH + ci0 + c] = c_lds[b * 16 + c];
    }
  }
}

extern "C" void kernel_launch(void* const* d_in, const int* in_sizes, int n_in,
                              void* d_out, int out_size, void* d_ws, size_t ws_size,
                              hipStream_t stream) {
  const float* x       = (const float*)d_in[0];
  const int* lengths   = (const int*)d_in[1];
  const float* Wi      = (const float*)d_in[2];
  const float* bi      = (const float*)d_in[3];
  const float* Ws      = (const float*)d_in[4];
  const float* bs      = (const float*)d_in[5];
  float* out = (float*)d_out;

  char* ws = (char*)d_ws;
  int* flags = (int*)ws;                                    // gemm tile counters (8KB)
  u64* hbuf  = (u64*)(ws + 8192);                           // 2 x 64KB tagged h
  unsigned short* pi = (unsigned short*)(ws + (1 << 20));   // [512][3072][32] bf16

  hipMemsetAsync(ws, 0, 8192 + 131072, stream);             // flags + tag re-poison
  fused_lstm<<<NWG + GK * GN, THR, 0, stream>>>(x, Wi, bi, Ws, bs, lengths,
                                                pi, hbuf, flags, out);
}

// Round 7
// 2096.091 us; speedup vs baseline: 1.2753x; 1.2753x over previous
//
#include <hip/hip_runtime.h>
#include <stdint.h>

typedef __attribute__((ext_vector_type(8))) short short8;
typedef __attribute__((ext_vector_type(4))) float f32x4;
typedef unsigned long long u64;

constexpr int cB = 32, cT = 512, cD = 512, cH = 512;
constexpr int cKI = 6 * cH;   // 3072
constexpr int NWG = 32;       // persistent lstm WGs (blockIdx 0..31)
constexpr int GWGS = 448;     // persistent gemm WGs (blockIdx 32..479)
constexpr int THR = 320;
constexpr int HP  = 520;      // h_lds row pitch (shorts)
constexpr int RNG = 3;        // pi prefetch ring depth
constexpr int PIP = 40;       // piL / gemm LDS row pitch (shorts)
constexpr int GK = 24, GN = 128;   // gemm tile grid (3072 tiles, nbk-major order)

// flags int layout (memset 0 each launch):
//   [0..31]    per-WG step flags (contiguous 128B line)
//   [512..639] per-nbk gemm tile counters, [640] total tiles done
constexpr int OFF_PIL  = 32 * HP * 2;                      // 33280
constexpr int OFF_PS   = OFF_PIL + RNG * 6 * 16 * PIP * 2; // 56320
constexpr int OFF_C    = OFF_PS + 5 * 16 * 36 * 4;         // 67840
constexpr int OFF_BS   = OFF_C + 512 * 4;                  // 69888
constexpr int OFF_LEN  = OFF_BS + 80 * 4;                  // 70208
constexpr int SMEM_SZ  = OFF_LEN + 32 * 4 + 16;            // 70352

__device__ __forceinline__ float bf2f(unsigned short u) {
  union { unsigned int i; float f; } x; x.i = ((unsigned int)u) << 16; return x.f;
}
__device__ __forceinline__ unsigned short f2bf(float f) {
  union { float f; unsigned int i; } x; x.f = f;
  return (unsigned short)((x.i + 0x7fffu + ((x.i >> 16) & 1u)) >> 16);
}
__device__ __forceinline__ float sigm(float v) { return 1.0f / (1.0f + __expf(-v)); }
__device__ __forceinline__ float tanh_f(float v) { return 2.0f / (1.0f + __expf(-2.0f * v)) - 1.0f; }

__global__ __launch_bounds__(THR, 1) void fused_lstm(
    const float* __restrict__ x,    // [B][T][D]
    const float* __restrict__ Wi,   // [6H][D]
    const float* __restrict__ bi,   // [6H]
    const float* __restrict__ Ws,   // [5H][H]
    const float* __restrict__ bs,   // [5H]
    const int* __restrict__ lengths,
    unsigned short* __restrict__ pi,   // [T][6H][B] bf16 (ws)
    unsigned short* __restrict__ hbuf, // [2][B][H] bf16 (ws)
    int* __restrict__ flags,
    float* __restrict__ out)           // ys[B][T][H], hT[B][H], cT[B][H]
{
  __shared__ __align__(16) unsigned char smem[SMEM_SZ];
  const int tid = threadIdx.x;
  const int lane = tid & 63;
  const int w = tid >> 6;

  if (blockIdx.x >= NWG) {
    // ========= Persistent GEMM: tiles in nbk-major (time) order =========
    const int wgg = (int)blockIdx.x - NWG;
    unsigned short* Ai = (unsigned short*)smem;            // 128 x PIP shorts
    unsigned short* Bi = (unsigned short*)(smem + 10240);  // 128 x PIP shorts
    const int wm = w & 1, wn = w >> 1;

    for (int tau = wgg; tau < GK * GN; tau += GWGS) {
      const int nbk = tau / GK, kb = tau % GK;
      const int k0 = kb * 128, n0 = nbk * 128;   // n = t*32 + b

      f32x4 acc[4][4];
      #pragma unroll
      for (int i = 0; i < 4; i++)
        #pragma unroll
        for (int j = 0; j < 4; j++) acc[i][j] = (f32x4){0.f, 0.f, 0.f, 0.f};

      for (int kk = 0; kk < cD; kk += 32) {
        __syncthreads();
        for (int idx = tid; idx < 1024; idx += THR) {
          int r = idx >> 3, ch = idx & 7;
          int na = n0 + r, bb = na & 31, tt = na >> 5;
          float4 va = *(const float4*)(x + ((size_t)bb * cT + tt) * cD + kk + ch * 4);
          ushort4 pa; pa.x = f2bf(va.x); pa.y = f2bf(va.y); pa.z = f2bf(va.z); pa.w = f2bf(va.w);
          *(ushort4*)(Ai + r * PIP + ch * 4) = pa;
          float4 vb = *(const float4*)(Wi + (size_t)(k0 + r) * cD + kk + ch * 4);
          ushort4 pb; pb.x = f2bf(vb.x); pb.y = f2bf(vb.y); pb.z = f2bf(vb.z); pb.w = f2bf(vb.w);
          *(ushort4*)(Bi + r * PIP + ch * 4) = pb;
        }
        __syncthreads();
        if (w < 4) {
          short8 af[4], bfr[4];
          const int q = lane >> 4;
          #pragma unroll
          for (int mi = 0; mi < 4; mi++)
            af[mi] = *(const short8*)(Ai + (wm * 64 + mi * 16 + (lane & 15)) * PIP + q * 8);
          #pragma unroll
          for (int ni = 0; ni < 4; ni++)
            bfr[ni] = *(const short8*)(Bi + (wn * 64 + ni * 16 + (lane & 15)) * PIP + q * 8);
          #pragma unroll
          for (int mi = 0; mi < 4; mi++)
            #pragma unroll
            for (int ni = 0; ni < 4; ni++)
              acc[mi][ni] = __builtin_amdgcn_mfma_f32_16x16x32_bf16(af[mi], bfr[ni], acc[mi][ni], 0, 0, 0);
        }
      }
      if (w < 4) {
        #pragma unroll
        for (int ni = 0; ni < 4; ni++) {
          int kl = wn * 64 + ni * 16 + (lane & 15);
          float bv = bi[k0 + kl];
          #pragma unroll
          for (int mi = 0; mi < 4; mi++) {
            int nl = wm * 64 + mi * 16 + (lane >> 4) * 4;
            int nb = n0 + nl;
            int b0 = nb & 31, tt = nb >> 5;
            f32x4 a = acc[mi][ni];
            unsigned short v0 = f2bf(a.x + bv), v1 = f2bf(a.y + bv);
            unsigned short v2 = f2bf(a.z + bv), v3 = f2bf(a.w + bv);
            u64 pk = (u64)v0 | ((u64)v1 << 16) | ((u64)v2 << 32) | ((u64)v3 << 48);
            __hip_atomic_store((u64*)(pi + ((size_t)tt * cKI + k0 + kl) * cB + b0), pk,
                               __ATOMIC_RELAXED, __HIP_MEMORY_SCOPE_AGENT);
          }
        }
      }
      __syncthreads();   // drains vmcnt: all pi stores acked before counter inc
      if (tid == 0) {
        __hip_atomic_fetch_add(flags + 512 + nbk, 1, __ATOMIC_RELAXED, __HIP_MEMORY_SCOPE_AGENT);
        __hip_atomic_fetch_add(flags + 640, 1, __ATOMIC_RELAXED, __HIP_MEMORY_SCOPE_AGENT);
      }
    }
    return;
  }

  // ================= LSTM persistent branch (R5 exchange, leaner) =================
  unsigned short* h_lds  = (unsigned short*)smem;                // [32][HP]
  unsigned short* piL    = (unsigned short*)(smem + OFF_PIL);    // [RNG][6*16][PIP]
  float* ps_lds          = (float*)(smem + OFF_PS);              // [5*16][36]
  float* c_lds           = (float*)(smem + OFF_C);               // [b*16+c]
  float* bs_lds          = (float*)(smem + OFF_BS);              // [80]
  int*   len_lds         = (int*)(smem + OFF_LEN);               // [32]

  const int wg = blockIdx.x;
  const int ci0 = wg * 16;
  const int mc = lane & 15;
  const int kq = lane >> 4;

  // Ws B-fragments in registers (verified layout)
  short8 bfrag[16];
  {
    const float* wsrow = Ws + (size_t)(w * cH + ci0 + mc) * cH;
    #pragma unroll
    for (int kt = 0; kt < 16; kt++) {
      float4 f0 = *(const float4*)(wsrow + kt * 32 + kq * 8);
      float4 f1 = *(const float4*)(wsrow + kt * 32 + kq * 8 + 4);
      short8 pk;
      pk[0] = (short)f2bf(f0.x); pk[1] = (short)f2bf(f0.y);
      pk[2] = (short)f2bf(f0.z); pk[3] = (short)f2bf(f0.w);
      pk[4] = (short)f2bf(f1.x); pk[5] = (short)f2bf(f1.y);
      pk[6] = (short)f2bf(f1.z); pk[7] = (short)f2bf(f1.w);
      bfrag[kt] = pk;
    }
  }
  if (tid < 80) bs_lds[tid] = bs[(tid >> 4) * cH + ci0 + (tid & 15)];
  if (tid < cB) len_lds[tid] = lengths[tid];
  for (int q = tid; q < 512; q += THR) c_lds[q] = 0.0f;
  for (int q = tid; q < 32 * HP / 4; q += THR) ((u64*)h_lds)[q] = 0ull;   // h0 = 0

  // initial pi readiness: nbk 0 covers t=0..3 (time-ordered production -> fast)
  {
    int guard = 0;
    while (__hip_atomic_load(flags + 512, __ATOMIC_RELAXED, __HIP_MEMORY_SCOPE_AGENT) < GK) {
      __builtin_amdgcn_s_sleep(8);
      if (++guard > 1000000) break;   // loud-fail, never wedge
    }
    asm volatile("" ::: "memory");
  }
  // pi ring prologue: t=0 -> slot0, t=1 -> slot1
  for (int s = 0; s < 2; s++) {
    const unsigned short* pit = pi + (size_t)s * cKI * cB;
    for (int j = tid; j < 384; j += THR) {
      int g = j >> 6, rem = j & 63, c = rem >> 2, q = rem & 3;
      uint4 v = *(const uint4*)(pit + ((size_t)g * cH + ci0 + c) * cB + q * 8);
      *(uint4*)(piL + s * (6 * 16 * PIP) + (g * 16 + c) * PIP + q * 8) = v;
    }
  }
  __syncthreads();

  bool all_ready = false;
  bool dead = false;
  float hprev0 = 0.0f, hprev1 = 0.0f;   // register-carried h for this thread's (b,c)

  for (int t = 0; t < cT; t++) {
    const bool last = (t == cT - 1);
    const bool pf = (t + 2) < cT;
    // [A] h batch load issue (agent scope; waits overlap the checks below)
    u64 hv[13];
    if (t > 0) {
      u64* hs = (u64*)(hbuf + (size_t)(t & 1) * cB * cH);
      #pragma unroll
      for (int k = 0; k < 13; k++) {
        int idx = tid + k * THR;
        if (idx < 4096)
          hv[k] = __hip_atomic_load(hs + idx, __ATOMIC_RELAXED, __HIP_MEMORY_SCOPE_AGENT);
      }
    }
    // [R] pi readiness for step t+2 (skipped once gemm fully done)
    if (pf && !all_ready) {
      int guard = 0;
      while (true) {
        int tot = __hip_atomic_load(flags + 640, __ATOMIC_RELAXED, __HIP_MEMORY_SCOPE_AGENT);
        if (tot >= GK * GN) { all_ready = true; break; }
        int v = __hip_atomic_load(flags + 512 + ((t + 2) >> 2), __ATOMIC_RELAXED, __HIP_MEMORY_SCOPE_AGENT);
        if (v >= GK) break;
        __builtin_amdgcn_s_sleep(4);
        if (++guard > 200000) { all_ready = true; break; }   // loud-fail
      }
      asm volatile("" ::: "memory");
    }
    // [P] pi loads for step t+2
    uint4 pv0, pv1;
    const int slot_w = (t + 2) % RNG;
    if (pf) {
      const unsigned short* pit = pi + (size_t)(t + 2) * cKI * cB;
      { int g = tid >> 6, rem = tid & 63, c = rem >> 2, q = rem & 3;
        pv0 = *(const uint4*)(pit + ((size_t)g * cH + ci0 + c) * cB + q * 8); }
      int j1 = tid + THR;
      if (j1 < 384) { int g = j1 >> 6, rem = j1 & 63, c = rem >> 2, q = rem & 3;
        pv1 = *(const uint4*)(pit + ((size_t)g * cH + ci0 + c) * cB + q * 8); }
    }
    // [C] staged h into LDS
    if (t > 0) {
      #pragma unroll
      for (int k = 0; k < 13; k++) {
        int idx = tid + k * THR;
        if (idx < 4096) {
          int b = idx >> 7, ch = idx & 127;
          *(u64*)(h_lds + b * HP + ch * 4) = hv[k];
        }
      }
    }
    __syncthreads();   // B1: h_lds visible

    // [D] MFMA: wave w computes ps[:, gate w] : 32x16, K=512 (Ws in registers)
    f32x4 acc0 = (f32x4){0.f,0.f,0.f,0.f}, acc1 = (f32x4){0.f,0.f,0.f,0.f};
    #pragma unroll
    for (int kt = 0; kt < 16; kt++) {
      int kc = kt * 4 + kq;
      short8 a0 = *(const short8*)(h_lds + mc * HP + kc * 8);
      short8 a1 = *(const short8*)(h_lds + (16 + mc) * HP + kc * 8);
      acc0 = __builtin_amdgcn_mfma_f32_16x16x32_bf16(a0, bfrag[kt], acc0, 0, 0, 0);
      acc1 = __builtin_amdgcn_mfma_f32_16x16x32_bf16(a1, bfrag[kt], acc1, 0, 0, 0);
    }
    {
      int r0 = kq * 4;   // C layout: col=lane&15 (=c), rows=(lane>>4)*4+reg (=b)
      *(f32x4*)(ps_lds + (w * 16 + mc) * 36 + r0) = acc0;
      *(f32x4*)(ps_lds + (w * 16 + mc) * 36 + r0 + 16) = acc1;
    }
    // [E] pi ring write for t+2
    if (pf) {
      { int g = tid >> 6, rem = tid & 63, c = rem >> 2, q = rem & 3;
        *(uint4*)(piL + slot_w * (6 * 16 * PIP) + (g * 16 + c) * PIP + q * 8) = pv0; }
      int j1 = tid + THR;
      if (j1 < 384) { int g = j1 >> 6, rem = j1 & 63, c = rem >> 2, q = rem & 3;
        *(uint4*)(piL + slot_w * (6 * 16 * PIP) + (g * 16 + c) * PIP + q * 8) = pv1; }
    }
    __syncthreads();   // B2: ps + ring visible

    // [F] gates, c-fast mapping: b=idx>>4, c=idx&15. hold in registers.
    const unsigned short* pl = piL + (t % RNG) * (6 * 16 * PIP);
    unsigned* hb32 = (unsigned*)(hbuf + (size_t)((t + 1) & 1) * cB * cH);
    float outv0 = 0.f, outv1 = 0.f;
    #pragma unroll
    for (int u = 0; u < 2; u++) {
      int idx = tid + u * THR;
      if (idx < 512) {
        int b = idx >> 4, c = idx & 15;
        int col = ci0 + c;
        float a_i = bf2f(pl[(0*16 + c)*PIP + b]) + ps_lds[(0*16 + c)*36 + b] + bs_lds[0*16 + c];
        float a_f = bf2f(pl[(1*16 + c)*PIP + b]) + ps_lds[(1*16 + c)*36 + b] + bs_lds[1*16 + c];
        float a_g = bf2f(pl[(2*16 + c)*PIP + b]) + ps_lds[(2*16 + c)*36 + b] + bs_lds[2*16 + c];
        float a_o = bf2f(pl[(3*16 + c)*PIP + b]) + ps_lds[(3*16 + c)*36 + b] + bs_lds[3*16 + c];
        float a_r = bf2f(pl[(4*16 + c)*PIP + b]) + ps_lds[(4*16 + c)*36 + b] + bs_lds[4*16 + c];
        float p5  = bf2f(pl[(5*16 + c)*PIP + b]);
        float gi = sigm(a_i), gf = sigm(a_f), gg = tanh_f(a_g), go = sigm(a_o), gr = sigm(a_r);
        float cold = c_lds[b * 16 + c];
        float cn = gi * gg + gf * cold;
        float ov = go * tanh_f(cn);
        ov = gr * ov + (1.0f - gr) * p5;
        bool m = (t < len_lds[b]);
        float hold = (u == 0) ? hprev0 : hprev1;
        float hn = m ? ov : hold;
        if (u == 0) hprev0 = hn; else hprev1 = hn;
        c_lds[b * 16 + c] = m ? cn : cold;
        float ovm = m ? ov : 0.0f;
        unsigned short hus = f2bf(hn);
        unsigned pr = (unsigned)__shfl_down((int)(unsigned)hus, 1);
        if (!last && (c & 1) == 0) {
          unsigned up = (unsigned)hus | (pr << 16);
          __hip_atomic_store(hb32 + ((b * cH + col) >> 1), up,
                             __ATOMIC_RELAXED, __HIP_MEMORY_SCOPE_AGENT);
        }
        if (last) {
          out[((size_t)b * cT + t) * cH + col] = ovm;
          out[(size_t)cB * cT * cH + (size_t)b * cH + col] = hn;   // hT
        } else {
          if (u == 0) outv0 = ovm; else outv1 = ovm;
        }
      }
    }
    if (!last) {
      __syncthreads();   // S3: drains publish stores (vmcnt(0) at barrier)
      if (tid == 0)
        __hip_atomic_store(&flags[wg], t + 2, __ATOMIC_RELAXED, __HIP_MEMORY_SCOPE_AGENT);
      // deferred out stores — overlap the poll window
      { int idx = tid;
        if (idx < 512) { int b = idx >> 4, c = idx & 15;
          out[((size_t)b * cT + t) * cH + ci0 + c] = outv0; }
        idx = tid + THR;
        if (idx < 512) { int b = idx >> 4, c = idx & 15;
          out[((size_t)b * cT + t) * cH + ci0 + c] = outv1; } }
      // all-thread poll on one 128B flag line; no release barrier needed
      if (!dead) {
        const int fl = lane & 31;
        int itc = 0;
        while (true) {
          int f = __hip_atomic_load(&flags[fl], __ATOMIC_RELAXED, __HIP_MEMORY_SCOPE_AGENT);
          if (__all(f >= t + 2)) break;
          if (++itc > 20000000) { dead = true; break; }   // loud-fail
        }
      }
    }
  }

  // cT from local c state (same thread mapping as gates -> no sync needed)
  #pragma unroll
  for (int u = 0; u < 2; u++) {
    int idx = tid + u * THR;
    if (idx < 512) {
      int b = idx >> 4, c = idx & 15;
      out[(size_t)cB * cT * cH + (size_t)cB * cH + (size_t)b * cH + ci0 + c] = c_lds[b * 16 + c];
    }
  }
}

extern "C" void kernel_launch(void* const* d_in, const int* in_sizes, int n_in,
                              void* d_out, int out_size, void* d_ws, size_t ws_size,
                              hipStream_t stream) {
  const float* x       = (const float*)d_in[0];
  const int* lengths   = (const int*)d_in[1];
  const float* Wi      = (const float*)d_in[2];
  const float* bi      = (const float*)d_in[3];
  const float* Ws      = (const float*)d_in[4];
  const float* bs      = (const float*)d_in[5];
  float* out = (float*)d_out;

  char* ws = (char*)d_ws;
  int* flags = (int*)ws;                                    // flags + tile counters (8KB)
  unsigned short* hbuf = (unsigned short*)(ws + 8192);      // 2*32*512*2 = 64KB
  unsigned short* pi   = (unsigned short*)(ws + (1 << 20)); // [512][3072][32] bf16

  hipMemsetAsync(flags, 0, 8192, stream);
  fused_lstm<<<NWG + GWGS, THR, 0, stream>>>(x, Wi, bi, Ws, bs, lengths,
                                             pi, hbuf, flags, out);
}

// Round 10
// 1825.445 us; speedup vs baseline: 1.4644x; 1.1483x over previous
//
#include <hip/hip_runtime.h>
#include <stdint.h>

typedef __attribute__((ext_vector_type(8))) short short8;
typedef __attribute__((ext_vector_type(4))) float f32x4;
typedef unsigned long long u64;

constexpr int cB = 32, cT = 512, cD = 512, cH = 512;
constexpr int cKI = 6 * cH;   // 3072
constexpr int NWG = 32;       // persistent lstm WGs (blockIdx 0..31)
constexpr int THR = 320;
constexpr int HP  = 520;      // h_lds row pitch (shorts)
constexpr int RNG = 3;        // pi prefetch ring depth
constexpr int PIP = 40;       // piL / gemm LDS row pitch (shorts)
constexpr int FPAD = 16;      // flag padding (ints) = 64B
constexpr int GK = 24, GN = 128;   // gemm tile grid (one tile per WG, R5-proven)

// flags int layout (memset 0 each launch, 8192B):
//   [0..511]   per-WG step flags (32 x FPAD, padded 64B lines)
//   [512..639] per-nbk gemm tile counters, [640] total tiles done
constexpr int OFF_PIL  = 32 * HP * 2;                      // 33280
constexpr int OFF_PS   = OFF_PIL + RNG * 6 * 16 * PIP * 2; // 56320
constexpr int OFF_C    = OFF_PS + 5 * 16 * 36 * 4;         // 67840
constexpr int OFF_BS   = OFF_C + 512 * 4;                  // 69888
constexpr int OFF_LEN  = OFF_BS + 80 * 4;                  // 70208
constexpr int OFF_MISC = OFF_LEN + 32 * 4;                 // 70336
constexpr int SMEM_SZ  = OFF_MISC + 16;                    // 70352

__device__ __forceinline__ float bf2f(unsigned short u) {
  union { unsigned int i; float f; } x; x.i = ((unsigned int)u) << 16; return x.f;
}
__device__ __forceinline__ unsigned short f2bf(float f) {
  union { float f; unsigned int i; } x; x.f = f;
  return (unsigned short)((x.i + 0x7fffu + ((x.i >> 16) & 1u)) >> 16);
}
__device__ __forceinline__ float sigm(float v) { return 1.0f / (1.0f + __expf(-v)); }
__device__ __forceinline__ float tanh_f(float v) { return 2.0f / (1.0f + __expf(-2.0f * v)) - 1.0f; }

__global__ __launch_bounds__(THR, 1) void fused_lstm(
    const float* __restrict__ x,    // [B][T][D]
    const float* __restrict__ Wi,   // [6H][D]
    const float* __restrict__ bi,   // [6H]
    const float* __restrict__ Ws,   // [5H][H]
    const float* __restrict__ bs,   // [5H]
    const int* __restrict__ lengths,
    unsigned short* __restrict__ pi,   // [T][6H][B] bf16 (ws)
    unsigned short* __restrict__ hbuf, // [2][B][H] bf16 (ws)
    int* __restrict__ flags,
    float* __restrict__ out)           // ys[B][T][H], hT[B][H], cT[B][H]
{
  __shared__ __align__(16) unsigned char smem[SMEM_SZ];
  const int tid = threadIdx.x;
  const int lane = tid & 63;
  const int w = tid >> 6;

  if (blockIdx.x >= NWG) {
    // ========= GEMM tile branch (R5-proven): one tile per WG, nbk-major order =========
    const int gb = (int)blockIdx.x - NWG;
    const int kb = gb % GK, nbk = gb / GK;
    const int k0 = kb * 128, n0 = nbk * 128;     // n = t*32 + b
    unsigned short* Ai = (unsigned short*)smem;            // 128 x PIP shorts
    unsigned short* Bi = (unsigned short*)(smem + 10240);  // 128 x PIP shorts
    const int wm = w & 1, wn = w >> 1;

    f32x4 acc[4][4];
    #pragma unroll
    for (int i = 0; i < 4; i++)
      #pragma unroll
      for (int j = 0; j < 4; j++) acc[i][j] = (f32x4){0.f, 0.f, 0.f, 0.f};

    for (int kk = 0; kk < cD; kk += 32) {
      __syncthreads();
      for (int idx = tid; idx < 1024; idx += THR) {
        int r = idx >> 3, ch = idx & 7;
        int na = n0 + r, bb = na & 31, tt = na >> 5;
        float4 va = *(const float4*)(x + ((size_t)bb * cT + tt) * cD + kk + ch * 4);
        ushort4 pa; pa.x = f2bf(va.x); pa.y = f2bf(va.y); pa.z = f2bf(va.z); pa.w = f2bf(va.w);
        *(ushort4*)(Ai + r * PIP + ch * 4) = pa;
        float4 vb = *(const float4*)(Wi + (size_t)(k0 + r) * cD + kk + ch * 4);
        ushort4 pb; pb.x = f2bf(vb.x); pb.y = f2bf(vb.y); pb.z = f2bf(vb.z); pb.w = f2bf(vb.w);
        *(ushort4*)(Bi + r * PIP + ch * 4) = pb;
      }
      __syncthreads();
      if (w < 4) {
        short8 af[4], bfr[4];
        const int q = lane >> 4;
        #pragma unroll
        for (int mi = 0; mi < 4; mi++)
          af[mi] = *(const short8*)(Ai + (wm * 64 + mi * 16 + (lane & 15)) * PIP + q * 8);
        #pragma unroll
        for (int ni = 0; ni < 4; ni++)
          bfr[ni] = *(const short8*)(Bi + (wn * 64 + ni * 16 + (lane & 15)) * PIP + q * 8);
        #pragma unroll
        for (int mi = 0; mi < 4; mi++)
          #pragma unroll
          for (int ni = 0; ni < 4; ni++)
            acc[mi][ni] = __builtin_amdgcn_mfma_f32_16x16x32_bf16(af[mi], bfr[ni], acc[mi][ni], 0, 0, 0);
      }
    }
    if (w < 4) {
      #pragma unroll
      for (int ni = 0; ni < 4; ni++) {
        int kl = wn * 64 + ni * 16 + (lane & 15);
        float bv = bi[k0 + kl];
        #pragma unroll
        for (int mi = 0; mi < 4; mi++) {
          int nl = wm * 64 + mi * 16 + (lane >> 4) * 4;
          int nb = n0 + nl;
          int b0 = nb & 31, tt = nb >> 5;
          f32x4 a = acc[mi][ni];
          unsigned short v0 = f2bf(a.x + bv), v1 = f2bf(a.y + bv);
          unsigned short v2 = f2bf(a.z + bv), v3 = f2bf(a.w + bv);
          u64 pk = (u64)v0 | ((u64)v1 << 16) | ((u64)v2 << 32) | ((u64)v3 << 48);
          __hip_atomic_store((u64*)(pi + ((size_t)tt * cKI + k0 + kl) * cB + b0), pk,
                             __ATOMIC_RELAXED, __HIP_MEMORY_SCOPE_AGENT);
        }
      }
    }
    __syncthreads();   // drains vmcnt: all pi stores acked before counter inc
    if (tid == 0) {
      __hip_atomic_fetch_add(flags + 512 + nbk, 1, __ATOMIC_RELAXED, __HIP_MEMORY_SCOPE_AGENT);
      __hip_atomic_fetch_add(flags + 640, 1, __ATOMIC_RELAXED, __HIP_MEMORY_SCOPE_AGENT);
    }
    return;
  }

  // ================= LSTM persistent branch (R5-proven exchange) + Lmax =================
  unsigned short* h_lds  = (unsigned short*)smem;                // [32][HP]
  unsigned short* piL    = (unsigned short*)(smem + OFF_PIL);    // [RNG][6*16][PIP]
  float* ps_lds          = (float*)(smem + OFF_PS);              // [5*16][36]
  float* c_lds           = (float*)(smem + OFF_C);               // [b*16+c]
  float* bs_lds          = (float*)(smem + OFF_BS);              // [80]
  int*   len_lds         = (int*)(smem + OFF_LEN);               // [32]
  int*   s_tr_p          = (int*)(smem + OFF_MISC);
  int*   s_all_p         = s_tr_p + 1;

  const int wg = blockIdx.x;
  const int ci0 = wg * 16;
  const int mc = lane & 15;
  const int kq = lane >> 4;

  // Ws B-fragments in registers (verified layout)
  short8 bfrag[16];
  {
    const float* wsrow = Ws + (size_t)(w * cH + ci0 + mc) * cH;
    #pragma unroll
    for (int kt = 0; kt < 16; kt++) {
      float4 f0 = *(const float4*)(wsrow + kt * 32 + kq * 8);
      float4 f1 = *(const float4*)(wsrow + kt * 32 + kq * 8 + 4);
      short8 pk;
      pk[0] = (short)f2bf(f0.x); pk[1] = (short)f2bf(f0.y);
      pk[2] = (short)f2bf(f0.z); pk[3] = (short)f2bf(f0.w);
      pk[4] = (short)f2bf(f1.x); pk[5] = (short)f2bf(f1.y);
      pk[6] = (short)f2bf(f1.z); pk[7] = (short)f2bf(f1.w);
      bfrag[kt] = pk;
    }
  }
  if (tid < 80) bs_lds[tid] = bs[(tid >> 4) * cH + ci0 + (tid & 15)];
  if (tid < cB) len_lds[tid] = lengths[tid];
  for (int q = tid; q < 512; q += THR) c_lds[q] = 0.0f;
  for (int q = tid; q < 32 * HP / 4; q += THR) ((u64*)h_lds)[q] = 0ull;   // h0 = 0

  // initial pi readiness: nbk 0 covers t=0..3; bounded (loud-fail, never wedge)
  if (tid == 0) {
    *s_all_p = 0;
    int it = 0;
    while (__hip_atomic_load(flags + 512, __ATOMIC_RELAXED, __HIP_MEMORY_SCOPE_AGENT) < GK) {
      __builtin_amdgcn_s_sleep(8);
      if (++it > 1000000) { *s_all_p = 1; break; }
    }
    *s_tr_p = 4;
  }
  __syncthreads();

  // pi ring prologue: t=0 -> slot0, t=1 -> slot1
  for (int s = 0; s < 2; s++) {
    const unsigned short* pit = pi + (size_t)s * cKI * cB;
    for (int j = tid; j < 384; j += THR) {
      int g = j >> 6, rem = j & 63, c = rem >> 2, q = rem & 3;
      uint4 v = *(const uint4*)(pit + ((size_t)g * cH + ci0 + c) * cB + q * 8);
      *(uint4*)(piL + s * (6 * 16 * PIP) + (g * 16 + c) * PIP + q * 8) = v;
    }
  }
  // zero own slice of hbuf[0]; init flag barrier (bounded poll)
  if (tid < 128) {
    int b = tid >> 2, q = tid & 3;
    __hip_atomic_store((u64*)hbuf + b * 128 + (ci0 >> 2) + q, 0ull,
                       __ATOMIC_RELAXED, __HIP_MEMORY_SCOPE_AGENT);
  }
  __syncthreads();   // drains zero-stores + LDS init
  if (tid == 0)
    __hip_atomic_store(&flags[wg * FPAD], 1, __ATOMIC_RELAXED, __HIP_MEMORY_SCOPE_AGENT);
  if (tid < 32) {
    int itc = 0;
    while (true) {
      int f = __hip_atomic_load(&flags[tid * FPAD], __ATOMIC_RELAXED, __HIP_MEMORY_SCOPE_AGENT);
      if (__all(f >= 1)) break;
      if (++itc > 20000000) break;   // loud-fail
    }
  }
  __syncthreads();

  // Lmax: for t >= max(lengths) every row is masked (h/c frozen, ys rows zero)
  // -> run scan to Tl only; zero-fill ys tail after the loop. Uniform across WGs.
  int Tl = 1;
  #pragma unroll
  for (int i = 0; i < 32; i++) { int L = len_lds[i]; Tl = (L > Tl) ? L : Tl; }

  float hprev0 = 0.0f, hprev1 = 0.0f;   // register-carried h for this thread's (b,c)

  for (int t = 0; t < Tl; t++) {
    const bool last = (t == Tl - 1);
    // [A] h batch load (agent scope, memory-side — proven path)
    u64 hv[13];
    if (t > 0) {
      u64* hs = (u64*)(hbuf + (size_t)(t & 1) * cB * cH);
      #pragma unroll
      for (int k = 0; k < 13; k++) {
        int idx = tid + k * THR;
        if (idx < 4096)
          hv[k] = __hip_atomic_load(hs + idx, __ATOMIC_RELAXED, __HIP_MEMORY_SCOPE_AGENT);
      }
    }
    // [P] pi loads for step t+2 (readiness: s_tr >= t+3 from prior step's tid64 wait)
    uint4 pv0, pv1;
    const bool pf = (t + 2) < Tl;
    const int slot_w = (t + 2) % RNG;
    if (pf) {
      const unsigned short* pit = pi + (size_t)(t + 2) * cKI * cB;
      { int g = tid >> 6, rem = tid & 63, c = rem >> 2, q = rem & 3;
        pv0 = *(const uint4*)(pit + ((size_t)g * cH + ci0 + c) * cB + q * 8); }
      int j1 = tid + THR;
      if (j1 < 384) { int g = j1 >> 6, rem = j1 & 63, c = rem >> 2, q = rem & 3;
        pv1 = *(const uint4*)(pit + ((size_t)g * cH + ci0 + c) * cB + q * 8); }
    }
    // [C] staged h into LDS
    if (t > 0) {
      #pragma unroll
      for (int k = 0; k < 13; k++) {
        int idx = tid + k * THR;
        if (idx < 4096) {
          int b = idx >> 7, ch = idx & 127;
          *(u64*)(h_lds + b * HP + ch * 4) = hv[k];
        }
      }
    }
    __syncthreads();   // B1: h_lds visible

    // [D] MFMA: wave w computes ps[:, gate w] : 32x16, K=512 (Ws in registers)
    f32x4 acc0 = (f32x4){0.f,0.f,0.f,0.f}, acc1 = (f32x4){0.f,0.f,0.f,0.f};
    #pragma unroll
    for (int kt = 0; kt < 16; kt++) {
      int kc = kt * 4 + kq;
      short8 a0 = *(const short8*)(h_lds + mc * HP + kc * 8);
      short8 a1 = *(const short8*)(h_lds + (16 + mc) * HP + kc * 8);
      acc0 = __builtin_amdgcn_mfma_f32_16x16x32_bf16(a0, bfrag[kt], acc0, 0, 0, 0);
      acc1 = __builtin_amdgcn_mfma_f32_16x16x32_bf16(a1, bfrag[kt], acc1, 0, 0, 0);
    }
    {
      int r0 = kq * 4;   // C layout: col=lane&15 (=c), rows=(lane>>4)*4+reg (=b)
      *(f32x4*)(ps_lds + (w * 16 + mc) * 36 + r0) = acc0;
      *(f32x4*)(ps_lds + (w * 16 + mc) * 36 + r0 + 16) = acc1;
    }
    // [E] pi ring write for t+2
    if (pf) {
      { int g = tid >> 6, rem = tid & 63, c = rem >> 2, q = rem & 3;
        *(uint4*)(piL + slot_w * (6 * 16 * PIP) + (g * 16 + c) * PIP + q * 8) = pv0; }
      int j1 = tid + THR;
      if (j1 < 384) { int g = j1 >> 6, rem = j1 & 63, c = rem >> 2, q = rem & 3;
        *(uint4*)(piL + slot_w * (6 * 16 * PIP) + (g * 16 + c) * PIP + q * 8) = pv1; }
    }
    __syncthreads();   // B2: ps + ring visible

    // [F] gates, c-fast mapping: b=idx>>4, c=idx&15. hold in registers.
    const unsigned short* pl = piL + (t % RNG) * (6 * 16 * PIP);
    unsigned* hb32 = (unsigned*)(hbuf + (size_t)((t + 1) & 1) * cB * cH);
    float outv0 = 0.f, outv1 = 0.f;
    #pragma unroll
    for (int u = 0; u < 2; u++) {
      int idx = tid + u * THR;
      if (idx < 512) {
        int b = idx >> 4, c = idx & 15;
        int col = ci0 + c;
        float a_i = bf2f(pl[(0*16 + c)*PIP + b]) + ps_lds[(0*16 + c)*36 + b] + bs_lds[0*16 + c];
        float a_f = bf2f(pl[(1*16 + c)*PIP + b]) + ps_lds[(1*16 + c)*36 + b] + bs_lds[1*16 + c];
        float a_g = bf2f(pl[(2*16 + c)*PIP + b]) + ps_lds[(2*16 + c)*36 + b] + bs_lds[2*16 + c];
        float a_o = bf2f(pl[(3*16 + c)*PIP + b]) + ps_lds[(3*16 + c)*36 + b] + bs_lds[3*16 + c];
        float a_r = bf2f(pl[(4*16 + c)*PIP + b]) + ps_lds[(4*16 + c)*36 + b] + bs_lds[4*16 + c];
        float p5  = bf2f(pl[(5*16 + c)*PIP + b]);
        float gi = sigm(a_i), gf = sigm(a_f), gg = tanh_f(a_g), go = sigm(a_o), gr = sigm(a_r);
        float cold = c_lds[b * 16 + c];
        float cn = gi * gg + gf * cold;
        float ov = go * tanh_f(cn);
        ov = gr * ov + (1.0f - gr) * p5;
        bool m = (t < len_lds[b]);
        float hold = (u == 0) ? hprev0 : hprev1;
        float hn = m ? ov : hold;
        if (u == 0) hprev0 = hn; else hprev1 = hn;
        c_lds[b * 16 + c] = m ? cn : cold;
        float ovm = m ? ov : 0.0f;
        unsigned short hus = f2bf(hn);
        unsigned pr = (unsigned)__shfl_down((int)(unsigned)hus, 1);
        if (!last && (c & 1) == 0) {
          unsigned up = (unsigned)hus | (pr << 16);
          __hip_atomic_store(hb32 + ((b * cH + col) >> 1), up,
                             __ATOMIC_RELAXED, __HIP_MEMORY_SCOPE_AGENT);
        }
        if (last) {
          out[((size_t)b * cT + t) * cH + col] = ovm;
          out[(size_t)cB * cT * cH + (size_t)b * cH + col] = hn;   // hT (frozen after Tl)
        } else {
          if (u == 0) outv0 = ovm; else outv1 = ovm;
        }
      }
    }
    if (!last) {
      __syncthreads();   // S3: drains publish stores (vmcnt(0) at barrier)
      if (tid == 0)
        __hip_atomic_store(&flags[wg * FPAD], t + 2, __ATOMIC_RELAXED, __HIP_MEMORY_SCOPE_AGENT);
      // deferred out stores — overlap the poll window
      { int idx = tid;
        if (idx < 512) { int b = idx >> 4, c = idx & 15;
          out[((size_t)b * cT + t) * cH + ci0 + c] = outv0; }
        idx = tid + THR;
        if (idx < 512) { int b = idx >> 4, c = idx & 15;
          out[((size_t)b * cT + t) * cH + ci0 + c] = outv1; } }
      if (tid < 32) {
        int itc = 0;
        while (true) {
          int f = __hip_atomic_load(&flags[tid * FPAD], __ATOMIC_RELAXED, __HIP_MEMORY_SCOPE_AGENT);
          if (__all(f >= t + 2)) break;
          if (++itc > 20000000) break;   // loud-fail
        }
      }
      if (tid == 64) {   // pi readiness advance, concurrent with flag poll; bounded
        if (!*s_all_p) {
          int tr = *s_tr_p;
          int need = t + 4; if (need > cT) need = cT;
          int guard = 0;
          while (tr < need) {
            int tot = __hip_atomic_load(flags + 640, __ATOMIC_RELAXED, __HIP_MEMORY_SCOPE_AGENT);
            if (tot >= GK * GN) { *s_all_p = 1; break; }
            int v = __hip_atomic_load(flags + 512 + (tr >> 2), __ATOMIC_RELAXED, __HIP_MEMORY_SCOPE_AGENT);
            if (v >= GK) { tr += 4; continue; }
            __builtin_amdgcn_s_sleep(8);
            if (++guard > 300000) { *s_all_p = 1; break; }
          }
          *s_tr_p = tr;
        }
      }
      __syncthreads();   // S4: release
    }
  }

  // ys tail zero-fill for t in [Tl, cT): all rows masked -> exact zeros.
  // j indexes (b, dt, q): b = j/(ntail*4), dt = (j%(ntail*4))>>2, q = j&3.
  {
    const int ntail = cT - Tl;
    if (ntail > 0) {
      const int per_b = ntail * 4;
      for (int j = tid; j < 32 * per_b; j += THR) {
        int b = j / per_b;
        int r2 = j - b * per_b;
        int dt = r2 >> 2, q = r2 & 3;
        *(float4*)(out + ((size_t)b * cT + Tl + dt) * cH + ci0 + q * 4) =
            (float4){0.f, 0.f, 0.f, 0.f};
      }
    }
  }

  // cT from local c state (same thread mapping as gates -> no sync needed)
  #pragma unroll
  for (int u = 0; u < 2; u++) {
    int idx = tid + u * THR;
    if (idx < 512) {
      int b = idx >> 4, c = idx & 15;
      out[(size_t)cB * cT * cH + (size_t)cB * cH + (size_t)b * cH + ci0 + c] = c_lds[b * 16 + c];
    }
  }
}

extern "C" void kernel_launch(void* const* d_in, const int* in_sizes, int n_in,
                              void* d_out, int out_size, void* d_ws, size_t ws_size,
                              hipStream_t stream) {
  const float* x       = (const float*)d_in[0];
  const int* lengths   = (const int*)d_in[1];
  const float* Wi      = (const float*)d_in[2];
  const float* bi      = (const float*)d_in[3];
  const float* Ws      = (const float*)d_in[4];
  const float* bs      = (const float*)d_in[5];
  float* out = (float*)d_out;

  char* ws = (char*)d_ws;
  int* flags = (int*)ws;                                    // flags + tile counters (8KB)
  unsigned short* hbuf = (unsigned short*)(ws + 8192);      // 2*32*512*2 = 64KB
  unsigned short* pi   = (unsigned short*)(ws + (1 << 20)); // [512][3072][32] bf16

  hipMemsetAsync(flags, 0, 8192, stream);
  fused_lstm<<<NWG + GK * GN, THR, 0, stream>>>(x, Wi, bi, Ws, bs, lengths,
                                                pi, hbuf, flags, out);
}